// Round 1
// baseline (1092.508 us; speedup 1.0000x reference)
//
#include <hip/hip_runtime.h>

#define Bn 4
#define Cn 64
#define On 64
#define Hn 128
#define Wn 128

#define NPIX (Bn * Hn * Wn)        // 65536
#define NOFF (Bn * 9 * Hn * Wn)    // 589824

// ---------------------------------------------------------------------------
// Repack the 4 weight tensors (OIHW, O in {18,18,18,9}) into
// wcat[(c*9 + kpos) * 64 + ch], ch in [0,63): 0..17 fc1, 18..35 fc2,
// 36..53 off, 54..62 mod.  Gives contiguous 63-float rows for the fused conv.
// ---------------------------------------------------------------------------
__global__ void repack_w(const float* __restrict__ w1, const float* __restrict__ w2,
                         const float* __restrict__ wo, const float* __restrict__ wm,
                         float* __restrict__ wcat) {
    int tid = blockIdx.x * 256 + threadIdx.x;
    if (tid >= 576 * 64) return;
    int s = tid >> 6;       // c*9 + kpos
    int j = tid & 63;
    int c = s / 9, kpos = s - 9 * (s / 9);
    float v = 0.f;
    if (j < 18)      v = w1[(j * Cn + c) * 9 + kpos];
    else if (j < 36) v = w2[((j - 18) * Cn + c) * 9 + kpos];
    else if (j < 54) v = wo[((j - 36) * Cn + c) * 9 + kpos];
    else if (j < 63) v = wm[((j - 54) * Cn + c) * 9 + kpos];
    wcat[s * 64 + j] = v;
}

// ---------------------------------------------------------------------------
// Fused: 4 convs (63 ch) + VAE gating -> absolute sample coords py,px + mask.
// One block per (b,h) row, one thread per w. 63 fp32 accumulators in VGPRs.
// ---------------------------------------------------------------------------
__global__ __launch_bounds__(128) void convgate(
    const float* __restrict__ x, const float* __restrict__ eps,
    const float* __restrict__ b1, const float* __restrict__ b2,
    const float* __restrict__ bo, const float* __restrict__ bm,
    const float* __restrict__ wcat,
    float* __restrict__ py, float* __restrict__ px, float* __restrict__ mk)
{
    int bh = blockIdx.x;
    int b = bh >> 7;
    int h = bh & 127;
    int w = threadIdx.x;

    float acc[63];
#pragma unroll
    for (int j = 0; j < 18; j++) acc[j] = b1[j];
#pragma unroll
    for (int j = 0; j < 18; j++) acc[18 + j] = b2[j];
#pragma unroll
    for (int j = 0; j < 18; j++) acc[36 + j] = bo[j];
#pragma unroll
    for (int j = 0; j < 9; j++)  acc[54 + j] = bm[j];

    const float* xb = x + b * (Cn * Hn * Wn);
    for (int c = 0; c < Cn; c++) {
        const float* xc = xb + c * (Hn * Wn);
#pragma unroll
        for (int ky = 0; ky < 3; ky++) {
            int yy = h + ky - 1;
            if (yy < 0 || yy >= Hn) continue;   // uniform across block
            const float* xr = xc + yy * Wn;
#pragma unroll
            for (int kx = 0; kx < 3; kx++) {
                int xx = w + kx - 1;
                float xv = (xx >= 0 && xx < Wn) ? xr[xx] : 0.f;
                const float* wrow = wcat + (c * 9 + ky * 3 + kx) * 64;
#pragma unroll
                for (int j = 0; j < 63; j++) acc[j] = fmaf(xv, wrow[j], acc[j]);
            }
        }
    }

    int epsbase = (b * 18) * (Hn * Wn) + h * Wn + w;
#pragma unroll
    for (int k = 0; k < 9; k++) {
        float offv[2];
#pragma unroll
        for (int d = 0; d < 2; d++) {
            int ch = 2 * k + d;
            float mu = fmaxf(acc[ch], 0.f);
            float lv = fmaxf(acc[18 + ch], 0.f);
            float e  = eps[epsbase + ch * (Hn * Wn)];
            float z  = fmaf(e, __expf(0.5f * lv), mu);
            float gate = 1.f / (1.f + __expf(-z));
            offv[d] = acc[36 + ch] * gate;
        }
        float m = 2.f / (1.f + __expf(-acc[54 + k]));
        int oidx = ((b * 9 + k) * Hn + h) * Wn + w;
        py[oidx] = (float)(h + (k / 3) - 1) + offv[0];
        px[oidx] = (float)(w + (k % 3) - 1) + offv[1];
        mk[oidx] = m;
    }
}

// ---------------------------------------------------------------------------
// Deformable conv. Block = 512 threads, 8 pixels/block.
// Phase A: stage sampled*mask [8][576] in LDS (stride 580: conflict-free +
//          16B aligned). Phase B: thread (o,p) dots 576 with w_reg row.
// ---------------------------------------------------------------------------
#define PPB 8
#define SMST 580

__global__ __launch_bounds__(512) void deform(
    const float* __restrict__ x,
    const float* __restrict__ py, const float* __restrict__ px,
    const float* __restrict__ mk,
    const float* __restrict__ wreg, float* __restrict__ out)
{
    __shared__ __align__(16) float sm[PPB * SMST];
    int tid = threadIdx.x;
    int pix0 = blockIdx.x * PPB;

    for (int idx = tid; idx < PPB * 576; idx += 512) {
        int p = idx / 576;
        int j = idx - p * 576;
        int c = j / 9;
        int k = j - c * 9;
        int pix = pix0 + p;
        int b = pix >> 14;
        int h = (pix >> 7) & 127;
        int w = pix & 127;
        int obase = ((b * 9 + k) * Hn + h) * Wn + w;
        float pyv = py[obase];
        float pxv = px[obase];
        float mv  = mk[obase];
        float y0f = floorf(pyv), x0f = floorf(pxv);
        float ly = pyv - y0f,  lx = pxv - x0f;
        int y0 = (int)y0f, x0 = (int)x0f;
        const float* xc = x + (b * Cn + c) * (Hn * Wn);

        float v = 0.f;
        {
            int yi = y0, xi = x0;
            float wg = (1.f - ly) * (1.f - lx);
            bool ok = (yi >= 0) && (yi < Hn) && (xi >= 0) && (xi < Wn);
            v += xc[min(max(yi, 0), Hn - 1) * Wn + min(max(xi, 0), Wn - 1)] * (ok ? wg : 0.f);
        }
        {
            int yi = y0, xi = x0 + 1;
            float wg = (1.f - ly) * lx;
            bool ok = (yi >= 0) && (yi < Hn) && (xi >= 0) && (xi < Wn);
            v += xc[min(max(yi, 0), Hn - 1) * Wn + min(max(xi, 0), Wn - 1)] * (ok ? wg : 0.f);
        }
        {
            int yi = y0 + 1, xi = x0;
            float wg = ly * (1.f - lx);
            bool ok = (yi >= 0) && (yi < Hn) && (xi >= 0) && (xi < Wn);
            v += xc[min(max(yi, 0), Hn - 1) * Wn + min(max(xi, 0), Wn - 1)] * (ok ? wg : 0.f);
        }
        {
            int yi = y0 + 1, xi = x0 + 1;
            float wg = ly * lx;
            bool ok = (yi >= 0) && (yi < Hn) && (xi >= 0) && (xi < Wn);
            v += xc[min(max(yi, 0), Hn - 1) * Wn + min(max(xi, 0), Wn - 1)] * (ok ? wg : 0.f);
        }
        sm[p * SMST + j] = v * mv;
    }
    __syncthreads();

    int o = tid >> 3;
    int p = tid & 7;
    int pix = pix0 + p;
    int b = pix >> 14;
    int h = (pix >> 7) & 127;
    int w = pix & 127;

    const float4* wr4 = reinterpret_cast<const float4*>(wreg + o * 576);
    const float4* sm4 = reinterpret_cast<const float4*>(&sm[p * SMST]);
    float acc = 0.f;
#pragma unroll 4
    for (int j = 0; j < 144; j++) {
        float4 a = wr4[j];
        float4 s = sm4[j];
        acc = fmaf(a.x, s.x, fmaf(a.y, s.y, fmaf(a.z, s.z, fmaf(a.w, s.w, acc))));
    }
    out[((b * On + o) * Hn + h) * Wn + w] = acc;
}

// ---------------------------------------------------------------------------
extern "C" void kernel_launch(void* const* d_in, const int* in_sizes, int n_in,
                              void* d_out, int out_size, void* d_ws, size_t ws_size,
                              hipStream_t stream) {
    const float* x     = (const float*)d_in[0];
    const float* eps   = (const float*)d_in[1];
    const float* w_fc1 = (const float*)d_in[2];
    const float* b_fc1 = (const float*)d_in[3];
    const float* w_fc2 = (const float*)d_in[4];
    const float* b_fc2 = (const float*)d_in[5];
    const float* w_off = (const float*)d_in[6];
    const float* b_off = (const float*)d_in[7];
    const float* w_mod = (const float*)d_in[8];
    const float* b_mod = (const float*)d_in[9];
    const float* w_reg = (const float*)d_in[10];

    float* ws   = (float*)d_ws;
    float* py   = ws;
    float* px   = ws + NOFF;
    float* mk   = ws + 2 * NOFF;
    float* wcat = ws + 3 * NOFF;   // 576*64 floats

    repack_w<<<144, 256, 0, stream>>>(w_fc1, w_fc2, w_off, w_mod, wcat);
    convgate<<<Bn * Hn, 128, 0, stream>>>(x, eps, b_fc1, b_fc2, b_off, b_mod,
                                          wcat, py, px, mk);
    deform<<<NPIX / PPB, 512, 0, stream>>>(x, py, px, mk, w_reg, (float*)d_out);
}

// Round 2
// 657.421 us; speedup vs baseline: 1.6618x; 1.6618x over previous
//
#include <hip/hip_runtime.h>

#define Bn 4
#define Cn 64
#define On 64
#define Hn 128
#define Wn 128

#define NPIX (Bn * Hn * Wn)        // 65536
#define NOFF (Bn * 9 * Hn * Wn)    // 589824

// ws layout (floats)
#define WS_PY   0
#define WS_PX   (WS_PY + NOFF)
#define WS_MK   (WS_PX + NOFF)
#define WS_WCAT (WS_MK + NOFF)            // 576*64
#define WS_WRT  (WS_WCAT + 576 * 64)      // 64*576 (k-major)
#define WS_XT   (WS_WRT + 64 * 576)       // 4*128*128*64 NHWC

// ---------------------------------------------------------------------------
// Repack 4 weight tensors into wcat[(c*9+kpos)*64 + ch] (ch: fc1|fc2|off|mod)
// ---------------------------------------------------------------------------
__global__ void repack_w(const float* __restrict__ w1, const float* __restrict__ w2,
                         const float* __restrict__ wo, const float* __restrict__ wm,
                         float* __restrict__ wcat) {
    int tid = blockIdx.x * 256 + threadIdx.x;
    if (tid >= 576 * 64) return;
    int s = tid >> 6;
    int j = tid & 63;
    int c = s / 9, kpos = s - 9 * (s / 9);
    float v = 0.f;
    if (j < 18)      v = w1[(j * Cn + c) * 9 + kpos];
    else if (j < 36) v = w2[((j - 18) * Cn + c) * 9 + kpos];
    else if (j < 54) v = wo[((j - 36) * Cn + c) * 9 + kpos];
    else if (j < 63) v = wm[((j - 54) * Cn + c) * 9 + kpos];
    wcat[s * 64 + j] = v;
}

// wregT[o][k*64+c] = wreg[o][c][k]
__global__ void repack_wreg(const float* __restrict__ wreg, float* __restrict__ wregT) {
    int tid = blockIdx.x * 256 + threadIdx.x;
    if (tid >= 64 * 576) return;
    int c = tid & 63;
    int k = (tid >> 6) % 9;
    int o = tid / 576;
    wregT[(o * 9 + k) * 64 + c] = wreg[(o * Cn + c) * 9 + k];
}

// ---------------------------------------------------------------------------
// NCHW -> NHWC transpose, LDS-tiled 64x64.
// ---------------------------------------------------------------------------
__global__ __launch_bounds__(256) void transpose_x(const float* __restrict__ x,
                                                   float* __restrict__ xT) {
    __shared__ float tl[64][65];
    int b = blockIdx.y;
    int hw0 = blockIdx.x * 64;
    int tid = threadIdx.x;
    for (int i = tid; i < 4096; i += 256) {
        int c = i >> 6, w = i & 63;
        tl[w][c] = x[(b * Cn + c) * (Hn * Wn) + hw0 + w];
    }
    __syncthreads();
    for (int i = tid; i < 4096; i += 256) {
        int w = i >> 6, c = i & 63;
        xT[(b * (Hn * Wn) + hw0 + w) * 64 + c] = tl[w][c];
    }
}

// ---------------------------------------------------------------------------
// Fused convs + gating. 512 threads = 4 c-groups (16 c each) x 128 pixels.
// 2-stage LDS tree reduce, gating by group 0.
// ---------------------------------------------------------------------------
__global__ __launch_bounds__(512) void convgate(
    const float* __restrict__ x, const float* __restrict__ eps,
    const float* __restrict__ b1, const float* __restrict__ b2,
    const float* __restrict__ bo, const float* __restrict__ bm,
    const float* __restrict__ wcat,
    float* __restrict__ py, float* __restrict__ px, float* __restrict__ mk)
{
    __shared__ float red[2 * 128 * 63];   // 63 KB
    int bh = blockIdx.x;
    int b = bh >> 7;
    int h = bh & 127;
    int tid = threadIdx.x;
    int g = tid >> 7;          // c-group
    int w = tid & 127;         // pixel

    float acc[63];
#pragma unroll
    for (int j = 0; j < 63; j++) acc[j] = 0.f;

    const float* xb = x + b * (Cn * Hn * Wn);
    int c0 = g * 16;
    for (int ci = 0; ci < 16; ci++) {
        int c = c0 + ci;
        const float* xc = xb + c * (Hn * Wn);
#pragma unroll
        for (int ky = 0; ky < 3; ky++) {
            int yy = h + ky - 1;
            if (yy < 0 || yy >= Hn) continue;
            const float* xr = xc + yy * Wn;
#pragma unroll
            for (int kx = 0; kx < 3; kx++) {
                int xx = w + kx - 1;
                float xv = (xx >= 0 && xx < Wn) ? xr[xx] : 0.f;
                const float* wrow = wcat + (c * 9 + ky * 3 + kx) * 64;
#pragma unroll
                for (int j = 0; j < 63; j++) acc[j] = fmaf(xv, wrow[j], acc[j]);
            }
        }
    }

    // reduce 4 groups -> group 0
    if (g >= 2) {
#pragma unroll
        for (int j = 0; j < 63; j++) red[((g - 2) * 128 + w) * 63 + j] = acc[j];
    }
    __syncthreads();
    if (g < 2) {
#pragma unroll
        for (int j = 0; j < 63; j++) acc[j] += red[(g * 128 + w) * 63 + j];
    }
    __syncthreads();
    if (g == 1) {
#pragma unroll
        for (int j = 0; j < 63; j++) red[w * 63 + j] = acc[j];
    }
    __syncthreads();
    if (g == 0) {
#pragma unroll
        for (int j = 0; j < 63; j++) acc[j] += red[w * 63 + j];

        int epsbase = (b * 18) * (Hn * Wn) + h * Wn + w;
#pragma unroll
        for (int k = 0; k < 9; k++) {
            float offv[2];
#pragma unroll
            for (int d = 0; d < 2; d++) {
                int ch = 2 * k + d;
                float mu = fmaxf(acc[ch] + b1[ch], 0.f);
                float lv = fmaxf(acc[18 + ch] + b2[ch], 0.f);
                float e  = eps[epsbase + ch * (Hn * Wn)];
                float z  = fmaf(e, __expf(0.5f * lv), mu);
                float gate = 1.f / (1.f + __expf(-z));
                offv[d] = (acc[36 + ch] + bo[ch]) * gate;
            }
            float m = 2.f / (1.f + __expf(-(acc[54 + k] + bm[k])));
            int oidx = ((b * 9 + k) * Hn + h) * Wn + w;
            py[oidx] = (float)(h + (k / 3) - 1) + offv[0];
            px[oidx] = (float)(w + (k % 3) - 1) + offv[1];
            mk[oidx] = m;
        }
    }
}

// ---------------------------------------------------------------------------
// Deformable conv v2: NHWC gather.
//  A0: 72 threads compute per-(p,k) corner float4-indices + weights*mask
//  A1: items (p,k,cg): 4 coalesced float4 loads, blend, store LDS [p][k*64+c]
//  B : thread (o,p) dots 576 with wregT row
// ---------------------------------------------------------------------------
#define PPB 8
#define SMST 580   // 576 + 4; /4 = 145

__global__ __launch_bounds__(512) void deform(
    const float* __restrict__ xT,
    const float* __restrict__ py, const float* __restrict__ px,
    const float* __restrict__ mk,
    const float* __restrict__ wregT, float* __restrict__ out)
{
    __shared__ __align__(16) float sm[PPB * SMST];
    __shared__ int4   cOff[PPB * 9];
    __shared__ float4 cWgt[PPB * 9];
    int tid = threadIdx.x;
    int pix0 = blockIdx.x * PPB;

    if (tid < PPB * 9) {
        int p = tid / 9;
        int k = tid - 9 * p;
        int pix = pix0 + p;
        int b = pix >> 14;
        int h = (pix >> 7) & 127;
        int w = pix & 127;
        int obase = ((b * 9 + k) * Hn + h) * Wn + w;
        float pyv = py[obase];
        float pxv = px[obase];
        float mv  = mk[obase];
        float y0f = floorf(pyv), x0f = floorf(pxv);
        float ly = pyv - y0f, lx = pxv - x0f;
        int y0 = (int)y0f, x0 = (int)x0f;
        int y1 = y0 + 1, x1 = x0 + 1;

        bool okY0 = (y0 >= 0) & (y0 < Hn);
        bool okY1 = (y1 >= 0) & (y1 < Hn);
        bool okX0 = (x0 >= 0) & (x0 < Wn);
        bool okX1 = (x1 >= 0) & (x1 < Wn);
        int y0c = min(max(y0, 0), Hn - 1), y1c = min(max(y1, 0), Hn - 1);
        int x0c = min(max(x0, 0), Wn - 1), x1c = min(max(x1, 0), Wn - 1);

        int base = b * (Hn * Wn);
        // float4-granule indices into xT
        int4 off;
        off.x = (base + y0c * Wn + x0c) * 16;
        off.y = (base + y0c * Wn + x1c) * 16;
        off.z = (base + y1c * Wn + x0c) * 16;
        off.w = (base + y1c * Wn + x1c) * 16;
        float4 wg;
        wg.x = (1.f - ly) * (1.f - lx) * ((okY0 & okX0) ? mv : 0.f);
        wg.y = (1.f - ly) * lx         * ((okY0 & okX1) ? mv : 0.f);
        wg.z = ly * (1.f - lx)         * ((okY1 & okX0) ? mv : 0.f);
        wg.w = ly * lx                 * ((okY1 & okX1) ? mv : 0.f);
        cOff[tid] = off;
        cWgt[tid] = wg;
    }
    __syncthreads();

    const float4* xT4 = reinterpret_cast<const float4*>(xT);
    for (int it = tid; it < PPB * 9 * 16; it += 512) {
        int cg = it & 15;
        int pk = it >> 4;           // p*9 + k
        int4   off = cOff[pk];
        float4 wg  = cWgt[pk];
        float4 c00 = xT4[off.x + cg];
        float4 c01 = xT4[off.y + cg];
        float4 c10 = xT4[off.z + cg];
        float4 c11 = xT4[off.w + cg];
        float4 v;
        v.x = fmaf(wg.x, c00.x, fmaf(wg.y, c01.x, fmaf(wg.z, c10.x, wg.w * c11.x)));
        v.y = fmaf(wg.x, c00.y, fmaf(wg.y, c01.y, fmaf(wg.z, c10.y, wg.w * c11.y)));
        v.z = fmaf(wg.x, c00.z, fmaf(wg.y, c01.z, fmaf(wg.z, c10.z, wg.w * c11.z)));
        v.w = fmaf(wg.x, c00.w, fmaf(wg.y, c01.w, fmaf(wg.z, c10.w, wg.w * c11.w)));
        int p = pk / 9;
        int k = pk - 9 * p;
        reinterpret_cast<float4*>(&sm[p * SMST])[k * 16 + cg] = v;
    }
    __syncthreads();

    int o = tid >> 3;
    int p = tid & 7;
    int pix = pix0 + p;
    int b = pix >> 14;
    int h = (pix >> 7) & 127;
    int w = pix & 127;

    const float4* wr4 = reinterpret_cast<const float4*>(wregT + o * 576);
    const float4* sm4 = reinterpret_cast<const float4*>(&sm[p * SMST]);
    float acc = 0.f;
#pragma unroll 4
    for (int j = 0; j < 144; j++) {
        float4 a = wr4[j];
        float4 s = sm4[j];
        acc = fmaf(a.x, s.x, fmaf(a.y, s.y, fmaf(a.z, s.z, fmaf(a.w, s.w, acc))));
    }
    out[((b * On + o) * Hn + h) * Wn + w] = acc;
}

// ---------------------------------------------------------------------------
extern "C" void kernel_launch(void* const* d_in, const int* in_sizes, int n_in,
                              void* d_out, int out_size, void* d_ws, size_t ws_size,
                              hipStream_t stream) {
    const float* x     = (const float*)d_in[0];
    const float* eps   = (const float*)d_in[1];
    const float* w_fc1 = (const float*)d_in[2];
    const float* b_fc1 = (const float*)d_in[3];
    const float* w_fc2 = (const float*)d_in[4];
    const float* b_fc2 = (const float*)d_in[5];
    const float* w_off = (const float*)d_in[6];
    const float* b_off = (const float*)d_in[7];
    const float* w_mod = (const float*)d_in[8];
    const float* b_mod = (const float*)d_in[9];
    const float* w_reg = (const float*)d_in[10];

    float* ws    = (float*)d_ws;
    float* py    = ws + WS_PY;
    float* px    = ws + WS_PX;
    float* mk    = ws + WS_MK;
    float* wcat  = ws + WS_WCAT;
    float* wregT = ws + WS_WRT;
    float* xT    = ws + WS_XT;

    repack_w<<<144, 256, 0, stream>>>(w_fc1, w_fc2, w_off, w_mod, wcat);
    repack_wreg<<<144, 256, 0, stream>>>(w_reg, wregT);
    transpose_x<<<dim3(256, 4), 256, 0, stream>>>(x, xT);
    convgate<<<Bn * Hn, 512, 0, stream>>>(x, eps, b_fc1, b_fc2, b_off, b_mod,
                                          wcat, py, px, mk);
    deform<<<NPIX / PPB, 512, 0, stream>>>(xT, py, px, mk, wregT, (float*)d_out);
}

// Round 3
// 171.655 us; speedup vs baseline: 6.3646x; 3.8299x over previous
//
#include <hip/hip_runtime.h>

typedef __attribute__((ext_vector_type(8))) __bf16 bf16x8;
typedef __attribute__((ext_vector_type(4))) float f32x4;
typedef unsigned short ushortT;

#define Bn 4
#define Hn 128
#define Wn 128
#define HP 130
#define WP 130

#define XP_ELEMS (Bn * HP * WP * 64)   // 4,326,400 ushorts
#define WCAT_ELEMS (64 * 576)
#define WREG_ELEMS (64 * 576)

__device__ __forceinline__ ushortT f2bf_u(float f) {
    unsigned int u = __float_as_uint(f);
    return (ushortT)((u + 0x8000u) >> 16);   // round-half-up to bf16
}

// ---------------------------------------------------------------------------
// wcatB[ch][kpos*64+c] bf16; ch: 0..17 fc1 | 18..35 fc2 | 36..53 off | 54..62 mod
// ---------------------------------------------------------------------------
__global__ void repack_wcat(const float* __restrict__ w1, const float* __restrict__ w2,
                            const float* __restrict__ wo, const float* __restrict__ wm,
                            ushortT* __restrict__ wcatB) {
    int tid = blockIdx.x * 256 + threadIdx.x;
    if (tid >= 64 * 576) return;
    int ch = tid / 576;
    int k = tid - ch * 576;
    int kpos = k >> 6, c = k & 63;
    float v = 0.f;
    if (ch < 18)      v = w1[(ch * 64 + c) * 9 + kpos];
    else if (ch < 36) v = w2[((ch - 18) * 64 + c) * 9 + kpos];
    else if (ch < 54) v = wo[((ch - 36) * 64 + c) * 9 + kpos];
    else if (ch < 63) v = wm[((ch - 54) * 64 + c) * 9 + kpos];
    wcatB[tid] = f2bf_u(v);
}

// wregB[o][kpos*64+c] bf16
__global__ void repack_wreg(const float* __restrict__ wr, ushortT* __restrict__ wregB) {
    int tid = blockIdx.x * 256 + threadIdx.x;
    if (tid >= 64 * 576) return;
    int o = tid / 576;
    int k = tid - o * 576;
    int kpos = k >> 6, c = k & 63;
    wregB[tid] = f2bf_u(wr[(o * 64 + c) * 9 + kpos]);
}

// ---------------------------------------------------------------------------
// x NCHW fp32 -> xp [b][y+1][x+1][c] bf16, zero borders (130x130 padded).
// One block per padded row.
// ---------------------------------------------------------------------------
__global__ __launch_bounds__(256) void pad_x(const float* __restrict__ x,
                                             ushortT* __restrict__ xp) {
    __shared__ float tl[64][129];
    int by = blockIdx.x;
    int b = by / HP;
    int y = by - b * HP;
    size_t rowbase = (size_t)(b * HP + y) * (WP * 64);
    int tid = threadIdx.x;
    if (y == 0 || y == HP - 1) {
        for (int i = tid; i < WP * 64; i += 256) xp[rowbase + i] = 0;
        return;
    }
    for (int i = tid; i < 64 * 128; i += 256) {
        int c = i >> 7, w = i & 127;
        tl[c][w] = x[((size_t)(b * 64 + c) * Hn + (y - 1)) * Wn + w];
    }
    __syncthreads();
    if (tid < 64) xp[rowbase + tid] = 0;
    else if (tid < 128) xp[rowbase + (size_t)(WP - 1) * 64 + (tid - 64)] = 0;
    for (int i = tid; i < 128 * 64; i += 256) {
        int w = i >> 6, c = i & 63;
        xp[rowbase + (size_t)(w + 1) * 64 + c] = f2bf_u(tl[c][w]);
    }
}

// ---------------------------------------------------------------------------
// Fused: conv-GEMM (MFMA) -> gating -> gather+deform-GEMM (MFMA).
// Block = 256 thr (4 waves) = one image row (128 pixels). M=64, N=128, K=576.
// Wave wv owns pixels wv*32..+31 (2 N-subtiles of 16). 16x16x32 bf16 MFMA:
//   A: row=lane&15, k=(lane>>4)*8+j ;  B: col=lane&15, k=(lane>>4)*8+j
//   D: col=lane&15, row=(lane>>4)*4+reg   [m89-verified]
// ---------------------------------------------------------------------------
__global__ __launch_bounds__(256) void fused(
    const ushortT* __restrict__ xp, const float* __restrict__ eps,
    const float* __restrict__ b1, const float* __restrict__ b2,
    const float* __restrict__ bo, const float* __restrict__ bm,
    const ushortT* __restrict__ wcatB, const ushortT* __restrict__ wregB,
    float* __restrict__ out)
{
    __shared__ float Cls[64 * 132];      // conv results [ch][pix], stride 132
    __shared__ int4   cOffL[9 * 128];    // per (k,pix): 4 corner elem-offsets
    __shared__ float4 cWgtL[9 * 128];    // per (k,pix): bilinear*mask weights

    int bh = blockIdx.x;
    int b = bh >> 7;
    int h = bh & 127;
    int tid = threadIdx.x;
    int l = tid & 63;
    int wv = tid >> 6;
    int lane15 = l & 15;
    int kl8 = (l >> 4) << 3;
    int wcol = wv << 5;

    const f32x4 zero4 = {0.f, 0.f, 0.f, 0.f};
    f32x4 acc[4][2];
#pragma unroll
    for (int mt = 0; mt < 4; ++mt) { acc[mt][0] = zero4; acc[mt][1] = zero4; }

    // ---------------- Phase 1: conv GEMM ----------------
#pragma unroll
    for (int kpos = 0; kpos < 9; ++kpos) {
        const int ky = kpos / 3, kx = kpos % 3;
        const ushortT* arow = wcatB + kpos * 64 + kl8;
        bf16x8 afr[4][2];
#pragma unroll
        for (int mt = 0; mt < 4; ++mt) {
#pragma unroll
            for (int ks = 0; ks < 2; ++ks)
                afr[mt][ks] = *(const bf16x8*)(arow + (mt * 16 + lane15) * 576 + ks * 32);
        }
        const ushortT* xrow = xp + (size_t)(b * HP + h + ky) * (WP * 64);
#pragma unroll
        for (int nt = 0; nt < 2; ++nt) {
            int pcol = wcol + nt * 16 + lane15 + kx;   // padded col
            const ushortT* bp = xrow + (size_t)pcol * 64 + kl8;
            bf16x8 bf0 = *(const bf16x8*)(bp);
            bf16x8 bf1 = *(const bf16x8*)(bp + 32);
#pragma unroll
            for (int mt = 0; mt < 4; ++mt) {
                acc[mt][nt] = __builtin_amdgcn_mfma_f32_16x16x32_bf16(afr[mt][0], bf0, acc[mt][nt], 0, 0, 0);
                acc[mt][nt] = __builtin_amdgcn_mfma_f32_16x16x32_bf16(afr[mt][1], bf1, acc[mt][nt], 0, 0, 0);
            }
        }
    }

    // conv C -> LDS
#pragma unroll
    for (int mt = 0; mt < 4; ++mt)
#pragma unroll
        for (int nt = 0; nt < 2; ++nt)
#pragma unroll
            for (int r = 0; r < 4; ++r)
                Cls[(mt * 16 + (l >> 4) * 4 + r) * 132 + wcol + nt * 16 + lane15] = acc[mt][nt][r];
    __syncthreads();

    // ---------------- Phase 2: gating (fp32) ----------------
    if (tid < 128) {
        int w = tid;
#pragma unroll
        for (int k = 0; k < 9; ++k) {
            int ky = k / 3, kx = k % 3;
            float offv[2];
#pragma unroll
            for (int d = 0; d < 2; ++d) {
                int ch = 2 * k + d;
                float mu = fmaxf(Cls[ch * 132 + w] + b1[ch], 0.f);
                float lv = fmaxf(Cls[(18 + ch) * 132 + w] + b2[ch], 0.f);
                float e  = eps[((size_t)(b * 18 + ch) * Hn + h) * Wn + w];
                float z  = fmaf(e, __expf(0.5f * lv), mu);
                float gate = 1.f / (1.f + __expf(-z));
                offv[d] = (Cls[(36 + ch) * 132 + w] + bo[ch]) * gate;
            }
            float m = 2.f / (1.f + __expf(-(Cls[(54 + k) * 132 + w] + bm[k])));
            float py = (float)(h + ky - 1) + offv[0];
            float px = (float)(w + kx - 1) + offv[1];
            float y0f = floorf(py), x0f = floorf(px);
            float ly = py - y0f, lx = px - x0f;
            int y0 = (int)y0f, x0 = (int)x0f;
            int y1 = y0 + 1, x1 = x0 + 1;
            bool okY0 = (y0 >= 0) & (y0 < Hn);
            bool okY1 = (y1 >= 0) & (y1 < Hn);
            bool okX0 = (x0 >= 0) & (x0 < Wn);
            bool okX1 = (x1 >= 0) & (x1 < Wn);
            int y0c = min(max(y0, 0), Hn - 1) + 1, y1c = min(max(y1, 0), Hn - 1) + 1;
            int x0c = min(max(x0, 0), Wn - 1) + 1, x1c = min(max(x1, 0), Wn - 1) + 1;
            int rb = b * HP;
            int4 co;
            co.x = ((rb + y0c) * WP + x0c) * 64;
            co.y = ((rb + y0c) * WP + x1c) * 64;
            co.z = ((rb + y1c) * WP + x0c) * 64;
            co.w = ((rb + y1c) * WP + x1c) * 64;
            float4 wq;
            wq.x = (1.f - ly) * (1.f - lx) * ((okY0 & okX0) ? m : 0.f);
            wq.y = (1.f - ly) * lx         * ((okY0 & okX1) ? m : 0.f);
            wq.z = ly * (1.f - lx)         * ((okY1 & okX0) ? m : 0.f);
            wq.w = ly * lx                 * ((okY1 & okX1) ? m : 0.f);
            cOffL[k * 128 + w] = co;
            cWgtL[k * 128 + w] = wq;
        }
    }
    __syncthreads();

    // ---------------- Phase 3: gather + deform GEMM ----------------
    f32x4 dcc[4][2];
#pragma unroll
    for (int mt = 0; mt < 4; ++mt) { dcc[mt][0] = zero4; dcc[mt][1] = zero4; }

    for (int kpos = 0; kpos < 9; ++kpos) {
        const ushortT* arow = wregB + kpos * 64 + kl8;
        bf16x8 afr[4][2];
#pragma unroll
        for (int mt = 0; mt < 4; ++mt) {
#pragma unroll
            for (int ks = 0; ks < 2; ++ks)
                afr[mt][ks] = *(const bf16x8*)(arow + (mt * 16 + lane15) * 576 + ks * 32);
        }
#pragma unroll
        for (int nt = 0; nt < 2; ++nt) {
            int pix = wcol + nt * 16 + lane15;
            int4 co   = cOffL[kpos * 128 + pix];
            float4 wq = cWgtL[kpos * 128 + pix];
#pragma unroll
            for (int ks = 0; ks < 2; ++ks) {
                int cofs = ks * 32 + kl8;
                bf16x8 v00 = *(const bf16x8*)(xp + co.x + cofs);
                bf16x8 v01 = *(const bf16x8*)(xp + co.y + cofs);
                bf16x8 v10 = *(const bf16x8*)(xp + co.z + cofs);
                bf16x8 v11 = *(const bf16x8*)(xp + co.w + cofs);
                bf16x8 bfr;
#pragma unroll
                for (int j = 0; j < 8; ++j) {
                    float f = wq.x * (float)v00[j];
                    f = fmaf(wq.y, (float)v01[j], f);
                    f = fmaf(wq.z, (float)v10[j], f);
                    f = fmaf(wq.w, (float)v11[j], f);
                    bfr[j] = (__bf16)f;
                }
#pragma unroll
                for (int mt = 0; mt < 4; ++mt)
                    dcc[mt][nt] = __builtin_amdgcn_mfma_f32_16x16x32_bf16(afr[mt][ks], bfr, dcc[mt][nt], 0, 0, 0);
            }
        }
    }

    // ---------------- Phase 4: write out ----------------
#pragma unroll
    for (int mt = 0; mt < 4; ++mt)
#pragma unroll
        for (int nt = 0; nt < 2; ++nt) {
            int w_ = wcol + nt * 16 + lane15;
#pragma unroll
            for (int r = 0; r < 4; ++r) {
                int o = mt * 16 + (l >> 4) * 4 + r;
                out[((size_t)(b * 64 + o) * Hn + h) * Wn + w_] = dcc[mt][nt][r];
            }
        }
}

// ---------------------------------------------------------------------------
extern "C" void kernel_launch(void* const* d_in, const int* in_sizes, int n_in,
                              void* d_out, int out_size, void* d_ws, size_t ws_size,
                              hipStream_t stream) {
    const float* x     = (const float*)d_in[0];
    const float* eps   = (const float*)d_in[1];
    const float* w_fc1 = (const float*)d_in[2];
    const float* b_fc1 = (const float*)d_in[3];
    const float* w_fc2 = (const float*)d_in[4];
    const float* b_fc2 = (const float*)d_in[5];
    const float* w_off = (const float*)d_in[6];
    const float* b_off = (const float*)d_in[7];
    const float* w_mod = (const float*)d_in[8];
    const float* b_mod = (const float*)d_in[9];
    const float* w_reg = (const float*)d_in[10];

    ushortT* xp    = (ushortT*)d_ws;
    ushortT* wcatB = xp + XP_ELEMS;
    ushortT* wregB = wcatB + WCAT_ELEMS;

    repack_wcat<<<144, 256, 0, stream>>>(w_fc1, w_fc2, w_off, w_mod, wcatB);
    repack_wreg<<<144, 256, 0, stream>>>(w_reg, wregB);
    pad_x<<<Bn * HP, 256, 0, stream>>>(x, xp);
    fused<<<Bn * Hn, 256, 0, stream>>>(xp, eps, b_fc1, b_fc2, b_off, b_mod,
                                       wcatB, wregB, (float*)d_out);
}